// Round 6
// baseline (3259.602 us; speedup 1.0000x reference)
//
#include <hip/hip_runtime.h>
#include <hip/hip_bf16.h>

typedef unsigned short u16;
typedef unsigned int u32;
typedef __attribute__((ext_vector_type(8))) __bf16 bf16x8;
typedef __attribute__((ext_vector_type(4))) float f32x4;

#define SEQ 4096
#define NBATCH 4
#define DMODEL 1024
#define DINNER 2048
#define DSTATE 128
#define NH 32
#define CONVD 2304
#define DPROJ 4384
#define ROWS (NBATCH*SEQ)   // 16384
#define TCH 256             // conv time-chunk
#define NCH (SEQ/TCH)       // 16 chunks -> 15 halo boundaries per batch
#define QS 256              // SSD chunk length
#define NQ (SEQ/QS)         // 16 SSD chunks
#define XOFF DINNER                   // 2048: conv'd x columns
#define BOFF (2*DINNER)               // 4096: B columns
#define COFF (2*DINNER + DSTATE)      // 4224: C columns
#define DTOFF (2*DINNER + 2*DSTATE)   // 4352: dt columns

__device__ __forceinline__ float bf2f(u16 v) {
    u32 x = ((u32)v) << 16;
    float f;
    __builtin_memcpy(&f, &x, 4);
    return f;
}
__device__ __forceinline__ u16 f2bf(float f) {
    u32 x;
    __builtin_memcpy(&x, &f, 4);
    u32 r = (x + 0x7FFFu + ((x >> 16) & 1u)) >> 16;
    return (u16)r;
}
__device__ __forceinline__ void unpack8(uint4 v, float* f) {
    u32 w0 = v.x, w1 = v.y, w2 = v.z, w3 = v.w;
    f[0] = bf2f((u16)(w0 & 0xFFFF)); f[1] = bf2f((u16)(w0 >> 16));
    f[2] = bf2f((u16)(w1 & 0xFFFF)); f[3] = bf2f((u16)(w1 >> 16));
    f[4] = bf2f((u16)(w2 & 0xFFFF)); f[5] = bf2f((u16)(w2 >> 16));
    f[6] = bf2f((u16)(w3 & 0xFFFF)); f[7] = bf2f((u16)(w3 >> 16));
}

// async global->LDS, 16B/lane: LDS dest = wave-uniform base + lane*16
__device__ __forceinline__ void async16(u16* lds_base, const u16* g) {
    __builtin_amdgcn_global_load_lds(
        (const __attribute__((address_space(1))) u32*)g,
        (__attribute__((address_space(3))) u32*)(u32)(size_t)lds_base,
        16, 0, 0);
}

// ---------------- f32 -> bf16 weight panel conversion ----------------
__global__ __launch_bounds__(256) void cvt_kernel(
    const float* __restrict__ in, u16* __restrict__ out, int n)
{
    int i = (blockIdx.x * 256 + threadIdx.x) * 4;
    if (i < n) {
        float4 v = *(const float4*)(in + i);
        u16 o[4] = { f2bf(v.x), f2bf(v.y), f2bf(v.z), f2bf(v.w) };
        *(uint2*)(out + i) = *(const uint2*)o;
    }
}

// ---------------- embedding: f32 table -> bf16 rows ----------------
__global__ __launch_bounds__(256) void embed_kernel(
    const int* __restrict__ x, const float* __restrict__ emb, u16* __restrict__ h)
{
    int row = blockIdx.x, tid = threadIdx.x;
    int id = x[row];
    float4 v = *(const float4*)(emb + (size_t)id * DMODEL + tid * 4);
    u16 o[4] = { f2bf(v.x), f2bf(v.y), f2bf(v.z), f2bf(v.w) };
    *(uint2*)(h + (size_t)row * DMODEL + tid * 4) = *(const uint2*)o;
}

// ---------------- rmsnorm (bf16 in, f32 weight -> bf16 out) ----------------
__global__ __launch_bounds__(256) void rmsnorm_kernel(
    const u16* __restrict__ in, const float* __restrict__ w, u16* __restrict__ out)
{
    int row = blockIdx.x, tid = threadIdx.x;
    const u16* r = in + (size_t)row * DMODEL + tid * 4;
    float v[4];
    v[0] = bf2f(r[0]); v[1] = bf2f(r[1]); v[2] = bf2f(r[2]); v[3] = bf2f(r[3]);
    float s = v[0]*v[0] + v[1]*v[1] + v[2]*v[2] + v[3]*v[3];
    #pragma unroll
    for (int off = 32; off; off >>= 1) s += __shfl_xor(s, off);
    __shared__ float red[4];
    if ((tid & 63) == 0) red[tid >> 6] = s;
    __syncthreads();
    float tot = red[0] + red[1] + red[2] + red[3];
    float sc = rsqrtf(tot * (1.f / DMODEL) + 1e-5f);
    float4 wv = *(const float4*)(w + tid * 4);
    u16* o = out + (size_t)row * DMODEL + tid * 4;
    u16 ov[4] = { f2bf(v[0] * sc * wv.x), f2bf(v[1] * sc * wv.y),
                  f2bf(v[2] * sc * wv.z), f2bf(v[3] * sc * wv.w) };
    *(uint2*)o = *(const uint2*)ov;
}

// ---------------- NT GEMM: C[M,N] = A[M,K] @ B[N,K]^T, bf16 in, fp32 acc ----------------
// global_load_lds staging (16B/lane); XOR swizzle folded into per-lane global column.
template<int EPI>
__global__ __launch_bounds__(256) void gemm_nt(
    const u16* __restrict__ A, const u16* __restrict__ B,
    int N, int K, int lda, int ntiles,
    u16* __restrict__ Cb, float* __restrict__ Cf)
{
    __shared__ __align__(16) u16 As[128 * 64];
    __shared__ __align__(16) u16 Bs[128 * 64];
    const int GM = 8;
    int gsz = GM * ntiles;
    int bid = blockIdx.x;
    int grp = bid / gsz, rem = bid % gsz;
    int m0 = (grp * GM + (rem % GM)) * 128;
    int n0 = (rem / GM) * 128;

    int tid = threadIdx.x;
    int lane = tid & 63, wv = tid >> 6;
    int wm = wv & 1, wn = wv >> 1;
    int q = lane >> 4, mr = lane & 15;

    f32x4 acc[4][4];
    #pragma unroll
    for (int i = 0; i < 4; i++)
        #pragma unroll
        for (int j = 0; j < 4; j++) acc[i][j] = (f32x4){0.f, 0.f, 0.f, 0.f};

    for (int kt = 0; kt < K; kt += 64) {
        #pragma unroll
        for (int ps = 0; ps < 4; ++ps) {
            int rb = ps * 32 + wv * 8;
            int r = rb + (lane >> 3);
            int scl = (lane & 7) ^ (r & 7);
            async16(&As[rb * 64], A + (size_t)(m0 + r) * lda + kt + scl * 8);
        }
        #pragma unroll
        for (int ps = 0; ps < 4; ++ps) {
            int rb = ps * 32 + wv * 8;
            int r = rb + (lane >> 3);
            int scl = (lane & 7) ^ (r & 7);
            int gn = n0 + r;
            if (gn < N)
                async16(&Bs[rb * 64], B + (size_t)gn * K + kt + scl * 8);
        }
        __syncthreads();
        #pragma unroll
        for (int kk = 0; kk < 2; ++kk) {
            bf16x8 af[4], bfr[4];
            #pragma unroll
            for (int mi = 0; mi < 4; ++mi) {
                int r = wm * 64 + mi * 16 + mr;
                int c = (kk * 4 + q) ^ (r & 7);
                af[mi] = *(const bf16x8*)&As[r * 64 + c * 8];
            }
            #pragma unroll
            for (int ni = 0; ni < 4; ++ni) {
                int r = wn * 64 + ni * 16 + mr;
                int c = (kk * 4 + q) ^ (r & 7);
                bfr[ni] = *(const bf16x8*)&Bs[r * 64 + c * 8];
            }
            #pragma unroll
            for (int mi = 0; mi < 4; ++mi)
                #pragma unroll
                for (int ni = 0; ni < 4; ++ni)
                    acc[mi][ni] = __builtin_amdgcn_mfma_f32_16x16x32_bf16(
                        af[mi], bfr[ni], acc[mi][ni], 0, 0, 0);
        }
        __syncthreads();
    }

    #pragma unroll
    for (int mi = 0; mi < 4; ++mi) {
        #pragma unroll
        for (int ni = 0; ni < 4; ++ni) {
            int gn = n0 + wn * 64 + ni * 16 + mr;
            if (gn < N) {
                #pragma unroll
                for (int r4 = 0; r4 < 4; ++r4) {
                    int gm = m0 + wm * 64 + mi * 16 + q * 4 + r4;
                    float v = acc[mi][ni][r4];
                    size_t idx = (size_t)gm * N + gn;
                    if (EPI == 0)      Cb[idx] = f2bf(v);
                    else if (EPI == 1) Cb[idx] = f2bf(bf2f(Cb[idx]) + v);
                    else               Cf[idx] = v;
                }
            }
        }
    }
}

// ---------------- halo save ----------------
__global__ __launch_bounds__(256) void halo_kernel(
    const u16* __restrict__ zx, u16* __restrict__ halo)
{
    int c = blockIdx.x * 256 + threadIdx.x;
    int idx = blockIdx.y;
    int b = blockIdx.z;
    int bi = idx / 3, r = idx % 3;
    int t = (bi + 1) * TCH - 3 + r;
    halo[(((size_t)b * (NCH - 1) + bi) * 3 + r) * CONVD + c] =
        zx[((size_t)b * SEQ + t) * DPROJ + DINNER + c];
}

// ---------------- depthwise causal conv + silu, in-place ----------------
__global__ __launch_bounds__(256) void convip_kernel(
    u16* __restrict__ zx, const float* __restrict__ cw, const float* __restrict__ cb,
    const u16* __restrict__ halo)
{
    int c = blockIdx.x * 256 + threadIdx.x;
    int ci = blockIdx.y;
    int b = blockIdx.z;
    float w0 = cw[c * 4 + 0], w1 = cw[c * 4 + 1];
    float w2 = cw[c * 4 + 2], w3 = cw[c * 4 + 3];
    float bias = cb[c];
    float h3 = 0.f, h2 = 0.f, h1 = 0.f;
    if (ci > 0) {
        const u16* hb = halo + (((size_t)b * (NCH - 1) + (ci - 1)) * 3) * CONVD + c;
        h3 = bf2f(hb[0 * CONVD]);
        h2 = bf2f(hb[1 * CONVD]);
        h1 = bf2f(hb[2 * CONVD]);
    }
    u16* p = zx + ((size_t)b * SEQ + (size_t)ci * TCH) * DPROJ + DINNER + c;
    #pragma unroll 4
    for (int t = 0; t < TCH; ++t) {
        float xr = bf2f(*p);
        float v = bias + w0 * h3 + w1 * h2 + w2 * h1 + w3 * xr;
        *p = f2bf(v / (1.f + expf(-v)));
        h3 = h2; h2 = h1; h1 = xr;
        p += DPROJ;
    }
}

// ================= SSD pass 1: per-chunk Hinc = Bw^T @ X (MFMA), dt cumsum =================
__global__ __launch_bounds__(256) void ssd_p1(
    const u16* __restrict__ zx,
    const float* __restrict__ dtb, const float* __restrict__ Alog,
    u16* __restrict__ cs, float* __restrict__ scum_g, float* __restrict__ sdt_g,
    float* __restrict__ dAck)
{
    int ck = blockIdx.x, hd = blockIdx.y, b = blockIdx.z;
    int tid = threadIdx.x;
    int wv = tid >> 6, lane = tid & 63, q = lane >> 4, mr = lane & 15;

    __shared__ __align__(16) u16 BwT[128 * 136];
    __shared__ __align__(16) u16 XT1[64 * 136];
    __shared__ float scumL[256], sdtL[256], swL[256];

    float An = -expf(Alog[hd]);
    float dtbF = dtb[hd];

    {
        size_t row = (size_t)b * SEQ + ck * QS + tid;
        float xx = bf2f(zx[row * DPROJ + DTOFF + hd]) + dtbF;
        float dt = (xx > 20.f) ? xx : log1pf(expf(xx));
        sdtL[tid] = dt;
        scumL[tid] = dt;
        __syncthreads();
        for (int ofs = 1; ofs < 256; ofs <<= 1) {
            float v = scumL[tid];
            float u = (tid >= ofs) ? scumL[tid - ofs] : 0.f;
            __syncthreads();
            scumL[tid] = v + u;
            __syncthreads();
        }
        float cumQ = scumL[255];
        swL[tid] = expf(An * (cumQ - scumL[tid])) * dt;
        size_t gbase = (((size_t)b * NH + hd) * NQ + ck) * QS;
        scum_g[gbase + tid] = scumL[tid];
        sdt_g[gbase + tid] = dt;
        if (tid == 0) dAck[((size_t)b * NH + hd) * NQ + ck] = expf(An * cumQ);
    }

    f32x4 hacc[2][4];
    #pragma unroll
    for (int i = 0; i < 2; i++)
        #pragma unroll
        for (int j = 0; j < 4; j++) hacc[i][j] = (f32x4){0.f, 0.f, 0.f, 0.f};

    int n0 = wv * 32;
    int jj = tid & 127, hi = tid >> 7;

    for (int half = 0; half < 2; ++half) {
        __syncthreads();
        size_t rowj = ((size_t)b * SEQ + ck * QS + half * 128 + jj) * DPROJ;
        float wj = swL[half * 128 + jj];
        #pragma unroll
        for (int it = 0; it < 8; ++it) {
            int nc = hi * 8 + it;
            uint4 v = *(const uint4*)(zx + rowj + BOFF + nc * 8);
            float f[8]; unpack8(v, f);
            #pragma unroll
            for (int u = 0; u < 8; ++u)
                BwT[(nc * 8 + u) * 136 + jj] = f2bf(f[u] * wj);
        }
        #pragma unroll
        for (int it = 0; it < 4; ++it) {
            int pc = hi * 4 + it;
            uint4 v = *(const uint4*)(zx + rowj + XOFF + hd * 64 + pc * 8);
            const u16* vp = (const u16*)&v;
            #pragma unroll
            for (int u = 0; u < 8; ++u)
                XT1[(pc * 8 + u) * 136 + jj] = vp[u];
        }
        __syncthreads();
        #pragma unroll
        for (int kk = 0; kk < 4; ++kk) {
            bf16x8 af[2], bx[4];
            #pragma unroll
            for (int it = 0; it < 2; ++it)
                af[it] = *(const bf16x8*)&BwT[(n0 + it * 16 + mr) * 136 + kk * 32 + q * 8];
            #pragma unroll
            for (int pt = 0; pt < 4; ++pt)
                bx[pt] = *(const bf16x8*)&XT1[(pt * 16 + mr) * 136 + kk * 32 + q * 8];
            #pragma unroll
            for (int it = 0; it < 2; ++it)
                #pragma unroll
                for (int pt = 0; pt < 4; ++pt)
                    hacc[it][pt] = __builtin_amdgcn_mfma_f32_16x16x32_bf16(
                        af[it], bx[pt], hacc[it][pt], 0, 0, 0);
        }
    }

    size_t basec = (((size_t)b * NH + hd) * NQ + ck) * 8192;
    #pragma unroll
    for (int it = 0; it < 2; ++it)
        #pragma unroll
        for (int pt = 0; pt < 4; ++pt)
            #pragma unroll
            for (int reg = 0; reg < 4; ++reg) {
                int n = n0 + it * 16 + q * 4 + reg;
                int p = pt * 16 + mr;
                cs[basec + p * 128 + n] = f2bf(hacc[it][pt][reg]);
            }
}

// ================= SSD pass 2: sequential chunk combine, Hinc -> Hstart =================
__global__ __launch_bounds__(256) void ssd_p2(
    u16* __restrict__ cs, const float* __restrict__ dAck)
{
    int hd = blockIdx.y, b = blockIdx.z;
    int off = blockIdx.x * 1024 + threadIdx.x * 4;
    size_t base = (((size_t)b * NH + hd) * NQ) * 8192 + off;
    const float* dA = dAck + ((size_t)b * NH + hd) * NQ;
    float c0 = 0.f, c1 = 0.f, c2 = 0.f, c3 = 0.f;
    for (int ck = 0; ck < NQ; ++ck) {
        u16* p = cs + base + (size_t)ck * 8192;
        uint2 v = *(const uint2*)p;
        float i0 = bf2f((u16)(v.x & 0xFFFF)), i1 = bf2f((u16)(v.x >> 16));
        float i2 = bf2f((u16)(v.y & 0xFFFF)), i3 = bf2f((u16)(v.y >> 16));
        u16 o[4] = { f2bf(c0), f2bf(c1), f2bf(c2), f2bf(c3) };
        *(uint2*)p = *(const uint2*)o;
        float a = dA[ck];
        c0 = fmaf(a, c0, i0); c1 = fmaf(a, c1, i1);
        c2 = fmaf(a, c2, i2); c3 = fmaf(a, c3, i3);
    }
}

// ================= SSD pass 3 (barrier-free jt loop, R0 structure) =================
// Flat grid 2048, XCD-colocated. Wave wv owns contiguous i-panel
// [wv*64, wv*64+64); waves skip fully-masked j-tiles (jtmax=2wv+2).
// S^T = B@C^T with operands direct from global; C-layout->A-layout via shuffles;
// decay factorized R_i*Q_j per j-tile.
// LB(256,4): LDS 35840*4=143KB<=160KB, VGPR 84<=128 cap -> 4 blocks/CU (was 3);
// latency-bound kernel (MfmaUtil 9%, VALU 20%, HBM 26%) -> more resident waves.
__global__ __launch_bounds__(256, 4) void ssd_p3(
    u16* __restrict__ zx,
    const float* __restrict__ Alog, const float* __restrict__ Dp,
    const u16* __restrict__ cs,
    const float* __restrict__ scum_g, const float* __restrict__ sdt_g)
{
    int bid = blockIdx.x;
    int xcd = bid & 7;
    int ixd = bid >> 3;              // 0..255
    int hd  = ixd & 31;
    int pr  = (xcd << 3) | (ixd >> 5);   // 0..63, constant per XCD
    int b   = pr >> 4;
    int ck  = pr & 15;

    int tid = threadIdx.x;
    int wv = tid >> 6, lane = tid & 63, q = lane >> 4, mr = lane & 15;
    int i0 = wv * 64;

    __shared__ __align__(16) u16 XT[64 * 264];   // x^T [p][j], pad 8
    __shared__ float scumL[256], sdtL[256];

    float An = -expf(Alog[hd]);
    float Dh = Dp[hd];

    {
        size_t gbase = (((size_t)b * NH + hd) * NQ + ck) * QS;
        scumL[tid] = scum_g[gbase + tid];
        sdtL[tid] = sdt_g[gbase + tid];
    }
    // stage X^T (thread = column j)
    {
        size_t rowj = ((size_t)b * SEQ + ck * QS + tid) * DPROJ + XOFF + hd * 64;
        #pragma unroll
        for (int pc = 0; pc < 8; ++pc) {
            uint4 v = *(const uint4*)(zx + rowj + pc * 8);
            const u16* vp = (const u16*)&v;
            #pragma unroll
            for (int u = 0; u < 8; ++u)
                XT[(pc * 8 + u) * 264 + tid] = vp[u];
        }
    }

    f32x4 Y[4][4];
    #pragma unroll
    for (int i = 0; i < 4; i++)
        #pragma unroll
        for (int j = 0; j < 4; j++) Y[i][j] = (f32x4){0.f, 0.f, 0.f, 0.f};

    const size_t rowC = ((size_t)b * SEQ + ck * QS) * DPROJ;
    size_t basec = (((size_t)b * NH + hd) * NQ + ck) * 8192;

    __syncthreads();   // the only barrier

    // Y1 = C @ Hstart (both operands direct from global), then row-decay scale
    #pragma unroll
    for (int kk = 0; kk < 4; ++kk) {
        bf16x8 cf[4], hb[4];
        #pragma unroll
        for (int it = 0; it < 4; ++it)
            cf[it] = *(const bf16x8*)(zx + rowC + (size_t)(i0 + it * 16 + mr) * DPROJ
                                      + COFF + kk * 32 + q * 8);
        #pragma unroll
        for (int pt = 0; pt < 4; ++pt)
            hb[pt] = *(const bf16x8*)(cs + basec + (size_t)(pt * 16 + mr) * 128
                                      + kk * 32 + q * 8);
        #pragma unroll
        for (int it = 0; it < 4; ++it)
            #pragma unroll
            for (int pt = 0; pt < 4; ++pt)
                Y[it][pt] = __builtin_amdgcn_mfma_f32_16x16x32_bf16(
                    cf[it], hb[pt], Y[it][pt], 0, 0, 0);
    }
    #pragma unroll
    for (int it = 0; it < 4; ++it)
        #pragma unroll
        for (int reg = 0; reg < 4; ++reg) {
            float f = expf(An * scumL[i0 + it * 16 + q * 4 + reg]);
            #pragma unroll
            for (int pt = 0; pt < 4; ++pt) Y[it][pt][reg] *= f;
        }

    // intra-chunk causal part: wave-local j-tiles of 32, no barriers
    int jtmax = 2 * wv + 2;
    for (int jt = 0; jt < jtmax; ++jt) {
        int jt0 = jt * 32;
        float ref = scumL[jt0 + 15];

        // S^T[j][i] = B @ C^T, operands direct from global (L1-hot)
        f32x4 ST[2][4];
        #pragma unroll
        for (int jm = 0; jm < 2; ++jm)
            #pragma unroll
            for (int it = 0; it < 4; ++it) ST[jm][it] = (f32x4){0.f, 0.f, 0.f, 0.f};
        #pragma unroll
        for (int kk = 0; kk < 4; ++kk) {
            bf16x8 ba[2], cf[4];
            #pragma unroll
            for (int jm = 0; jm < 2; ++jm)
                ba[jm] = *(const bf16x8*)(zx + rowC + (size_t)(jt0 + jm * 16 + mr) * DPROJ
                                          + BOFF + kk * 32 + q * 8);
            #pragma unroll
            for (int it = 0; it < 4; ++it)
                cf[it] = *(const bf16x8*)(zx + rowC + (size_t)(i0 + it * 16 + mr) * DPROJ
                                          + COFF + kk * 32 + q * 8);
            #pragma unroll
            for (int jm = 0; jm < 2; ++jm)
                #pragma unroll
                for (int it = 0; it < 4; ++it)
                    ST[jm][it] = __builtin_amdgcn_mfma_f32_16x16x32_bf16(
                        ba[jm], cf[it], ST[jm][it], 0, 0, 0);
        }

        // decay factors: Q_j (lanes 0..31 domain), R_i per it
        int jq = jt0 + (lane & 31);
        float Qv = expf(An * (ref - scumL[jq])) * sdtL[jq];
        float Rit[4];
        #pragma unroll
        for (int it = 0; it < 4; ++it)
            Rit[it] = expf(An * (scumL[i0 + it * 16 + mr] - ref));

        bf16x8 xf[4];
        #pragma unroll
        for (int pt = 0; pt < 4; ++pt)
            xf[pt] = *(const bf16x8*)&XT[(pt * 16 + mr) * 264 + jt0 + q * 8];

        // assemble M A-frags (shuffle transpose of S^T) and accumulate Y += M @ X
        #pragma unroll
        for (int it = 0; it < 4; ++it) {
            u16 marr[8];
            #pragma unroll
            for (int u = 0; u < 8; ++u) {
                int src = (2 * (q & 1) + (u >> 2)) * 16 + mr;
                float s0 = __shfl(ST[0][it][u & 3], src);
                float s1 = __shfl(ST[1][it][u & 3], src);
                float sj = (q < 2) ? s0 : s1;
                float Qu = __shfl(Qv, 8 * q + u);
                int jg = jt0 + 8 * q + u;
                int ig = i0 + it * 16 + mr;
                float m = (jg <= ig) ? Rit[it] * Qu * sj : 0.f;
                marr[u] = f2bf(m);
            }
            bf16x8 mf;
            __builtin_memcpy(&mf, marr, 16);
            #pragma unroll
            for (int pt = 0; pt < 4; ++pt)
                Y[it][pt] = __builtin_amdgcn_mfma_f32_16x16x32_bf16(
                    mf, xf[pt], Y[it][pt], 0, 0, 0);
        }
    }

    // epilogue: y = Y + D*x, write over x cols
    #pragma unroll
    for (int it = 0; it < 4; ++it)
        #pragma unroll
        for (int pt = 0; pt < 4; ++pt)
            #pragma unroll
            for (int reg = 0; reg < 4; ++reg) {
                int i = i0 + it * 16 + q * 4 + reg;
                int p = pt * 16 + mr;
                float xv = bf2f(XT[p * 264 + i]);
                float val = Y[it][pt][reg] + Dh * xv;
                zx[((size_t)b * SEQ + ck * QS + i) * DPROJ + XOFF + hd * 64 + p] = f2bf(val);
            }
}

// ---------------- y * silu(z) then rmsnorm(gnorm_w f32) ----------------
__global__ __launch_bounds__(256) void gatenorm_kernel(
    u16* __restrict__ zx, const float* __restrict__ gw)
{
    int row = blockIdx.x, tid = threadIdx.x;
    u16* zr = zx + (size_t)row * DPROJ;
    float v[8];
    float s = 0.f;
    #pragma unroll
    for (int i = 0; i < 8; ++i) {
        int idx = i * 256 + tid;
        float zv = bf2f(zr[idx]);
        float gate = zv / (1.f + expf(-zv));
        float val = bf2f(zr[DINNER + idx]) * gate;
        v[i] = val;
        s += val * val;
    }
    #pragma unroll
    for (int off = 32; off; off >>= 1) s += __shfl_xor(s, off);
    __shared__ float red[4];
    if ((tid & 63) == 0) red[tid >> 6] = s;
    __syncthreads();
    float tot = red[0] + red[1] + red[2] + red[3];
    float sc = rsqrtf(tot * (1.f / DINNER) + 1e-5f);
    #pragma unroll
    for (int i = 0; i < 8; ++i) {
        int idx = i * 256 + tid;
        zr[DINNER + idx] = f2bf(v[i] * sc * gw[idx]);
    }
}

extern "C" void kernel_launch(void* const* d_in, const int* in_sizes, int n_in,
                              void* d_out, int out_size, void* d_ws, size_t ws_size,
                              hipStream_t stream) {
    const int*   x          = (const int*)d_in[0];
    const float* emb        = (const float*)d_in[1];
    const float* in_proj_w  = (const float*)d_in[2];
    const float* conv_w     = (const float*)d_in[3];
    const float* conv_b     = (const float*)d_in[4];
    const float* dt_bias    = (const float*)d_in[5];
    const float* A_log      = (const float*)d_in[6];
    const float* Dp         = (const float*)d_in[7];
    const float* gnorm_w    = (const float*)d_in[8];
    const float* out_proj_w = (const float*)d_in[9];
    const float* rms_w      = (const float*)d_in[10];
    const float* norm_f_w   = (const float*)d_in[11];
    const float* lm_head_w  = (const float*)d_in[12];
    float* out = (float*)d_out;

    char* w = (char*)d_ws;
    u16* h       = (u16*)w; w += (size_t)ROWS * DMODEL * 2;
    u16* zx      = (u16*)w; w += (size_t)ROWS * DPROJ * 2;
    char* scratch = w;      w += (size_t)NBATCH * NH * NQ * 8192 * 2;  // 32 MiB
    u16* wA      = (u16*)w; w += (size_t)DPROJ * DMODEL * 2;
    u16* wB      = (u16*)w; w += (size_t)DMODEL * DINNER * 2;
    float* scum_g = (float*)w; w += (size_t)NBATCH * NH * NQ * QS * 4;
    float* sdt_g  = (float*)w; w += (size_t)NBATCH * NH * NQ * QS * 4;
    float* dAck   = (float*)w; w += (size_t)NBATCH * NH * NQ * 4;
    u16* normed  = (u16*)scratch;
    u16* halo    = (u16*)scratch;
    u16* cs      = (u16*)scratch;

    embed_kernel<<<ROWS, 256, 0, stream>>>(x, emb, h);

    const int nInW = DPROJ * DMODEL;
    const int nOutW = DMODEL * DINNER;
    const int nHeadW = 64 * DMODEL;

    for (int l = 0; l < 4; ++l) {
        cvt_kernel<<<nInW / 1024, 256, 0, stream>>>(
            in_proj_w + (size_t)l * nInW, wA, nInW);
        cvt_kernel<<<nOutW / 1024, 256, 0, stream>>>(
            out_proj_w + (size_t)l * nOutW, wB, nOutW);
        rmsnorm_kernel<<<ROWS, 256, 0, stream>>>(h, rms_w + l * DMODEL, normed);
        gemm_nt<0><<<128 * 35, 256, 0, stream>>>(
            normed, wA, DPROJ, DMODEL, DMODEL, 35, zx, nullptr);
        halo_kernel<<<dim3(9, (NCH - 1) * 3, NBATCH), 256, 0, stream>>>(zx, halo);
        convip_kernel<<<dim3(9, NCH, NBATCH), 256, 0, stream>>>(
            zx, conv_w + (size_t)l * CONVD * 4, conv_b + (size_t)l * CONVD, halo);
        ssd_p1<<<dim3(NQ, NH, NBATCH), 256, 0, stream>>>(
            zx, dt_bias + l * NH, A_log + l * NH, cs, scum_g, sdt_g, dAck);
        ssd_p2<<<dim3(8, NH, NBATCH), 256, 0, stream>>>(cs, dAck);
        ssd_p3<<<NQ * NH * NBATCH, 256, 0, stream>>>(
            zx, A_log + l * NH, Dp + l * NH, cs, scum_g, sdt_g);
        gatenorm_kernel<<<ROWS, 256, 0, stream>>>(zx, gnorm_w + (size_t)l * DINNER);
        gemm_nt<1><<<128 * 8, 256, 0, stream>>>(
            zx + DINNER, wB, DMODEL, DINNER, DPROJ, 8, h, nullptr);
    }

    rmsnorm_kernel<<<ROWS, 256, 0, stream>>>(h, norm_f_w, normed);
    cvt_kernel<<<nHeadW / 1024, 256, 0, stream>>>(lm_head_w, wA, nHeadW);
    gemm_nt<2><<<128 * 1, 256, 0, stream>>>(
        normed, wA, 64, DMODEL, DMODEL, 1, nullptr, out);
}

// Round 7
// 2593.124 us; speedup vs baseline: 1.2570x; 1.2570x over previous
//
#include <hip/hip_runtime.h>
#include <hip/hip_bf16.h>

typedef unsigned short u16;
typedef unsigned int u32;
typedef __attribute__((ext_vector_type(8))) __bf16 bf16x8;
typedef __attribute__((ext_vector_type(4))) __bf16 bf16x4;
typedef __attribute__((ext_vector_type(4))) short s16x4;
typedef __attribute__((ext_vector_type(4))) float f32x4;

#define SEQ 4096
#define NBATCH 4
#define DMODEL 1024
#define DINNER 2048
#define DSTATE 128
#define NH 32
#define CONVD 2304
#define DPROJ 4384
#define ROWS (NBATCH*SEQ)   // 16384
#define TCH 256             // conv time-chunk
#define NCH (SEQ/TCH)       // 16 chunks -> 15 halo boundaries per batch
#define QS 256              // SSD chunk length
#define NQ (SEQ/QS)         // 16 SSD chunks
#define XOFF DINNER                   // 2048: conv'd x columns
#define BOFF (2*DINNER)               // 4096: B columns
#define COFF (2*DINNER + DSTATE)      // 4224: C columns
#define DTOFF (2*DINNER + 2*DSTATE)   // 4352: dt columns

__device__ __forceinline__ float bf2f(u16 v) {
    u32 x = ((u32)v) << 16;
    float f;
    __builtin_memcpy(&f, &x, 4);
    return f;
}
__device__ __forceinline__ u16 f2bf(float f) {
    u32 x;
    __builtin_memcpy(&x, &f, 4);
    u32 r = (x + 0x7FFFu + ((x >> 16) & 1u)) >> 16;
    return (u16)r;
}
__device__ __forceinline__ void unpack8(uint4 v, float* f) {
    u32 w0 = v.x, w1 = v.y, w2 = v.z, w3 = v.w;
    f[0] = bf2f((u16)(w0 & 0xFFFF)); f[1] = bf2f((u16)(w0 >> 16));
    f[2] = bf2f((u16)(w1 & 0xFFFF)); f[3] = bf2f((u16)(w1 >> 16));
    f[4] = bf2f((u16)(w2 & 0xFFFF)); f[5] = bf2f((u16)(w2 >> 16));
    f[6] = bf2f((u16)(w3 & 0xFFFF)); f[7] = bf2f((u16)(w3 >> 16));
}

// 16x16x16 bf16 MFMA: A-frag k = q*4+u matches the 16x16 D-layout row = q*4+reg,
// so the S^T MFMA output feeds this A-operand with ZERO cross-lane shuffles.
// (Numerically verified on-harness in R2/R3/R4 runs.)
__device__ __forceinline__ f32x4 mfma16bf(bf16x4 a, bf16x4 b, f32x4 c) {
#if __has_builtin(__builtin_amdgcn_mfma_f32_16x16x16bf16_1k)
    s16x4 as, bs;
    __builtin_memcpy(&as, &a, 8);
    __builtin_memcpy(&bs, &b, 8);
    return __builtin_amdgcn_mfma_f32_16x16x16bf16_1k(as, bs, c, 0, 0, 0);
#else
    f32x4 d = c;
    asm volatile("v_mfma_f32_16x16x16_bf16 %0, %1, %2, %0"
                 : "+v"(d) : "v"(a), "v"(b));
    return d;
#endif
}

// async global->LDS, 16B/lane: LDS dest = wave-uniform base + lane*16
__device__ __forceinline__ void async16(u16* lds_base, const u16* g) {
    __builtin_amdgcn_global_load_lds(
        (const __attribute__((address_space(1))) u32*)g,
        (__attribute__((address_space(3))) u32*)(u32)(size_t)lds_base,
        16, 0, 0);
}

// ---------------- f32 -> bf16 weight panel conversion ----------------
__global__ __launch_bounds__(256) void cvt_kernel(
    const float* __restrict__ in, u16* __restrict__ out, int n)
{
    int i = (blockIdx.x * 256 + threadIdx.x) * 4;
    if (i < n) {
        float4 v = *(const float4*)(in + i);
        u16 o[4] = { f2bf(v.x), f2bf(v.y), f2bf(v.z), f2bf(v.w) };
        *(uint2*)(out + i) = *(const uint2*)o;
    }
}

// ---------------- embedding: f32 table -> bf16 rows ----------------
__global__ __launch_bounds__(256) void embed_kernel(
    const int* __restrict__ x, const float* __restrict__ emb, u16* __restrict__ h)
{
    int row = blockIdx.x, tid = threadIdx.x;
    int id = x[row];
    float4 v = *(const float4*)(emb + (size_t)id * DMODEL + tid * 4);
    u16 o[4] = { f2bf(v.x), f2bf(v.y), f2bf(v.z), f2bf(v.w) };
    *(uint2*)(h + (size_t)row * DMODEL + tid * 4) = *(const uint2*)o;
}

// ---------------- rmsnorm (bf16 in, f32 weight -> bf16 out) ----------------
__global__ __launch_bounds__(256) void rmsnorm_kernel(
    const u16* __restrict__ in, const float* __restrict__ w, u16* __restrict__ out)
{
    int row = blockIdx.x, tid = threadIdx.x;
    const u16* r = in + (size_t)row * DMODEL + tid * 4;
    float v[4];
    v[0] = bf2f(r[0]); v[1] = bf2f(r[1]); v[2] = bf2f(r[2]); v[3] = bf2f(r[3]);
    float s = v[0]*v[0] + v[1]*v[1] + v[2]*v[2] + v[3]*v[3];
    #pragma unroll
    for (int off = 32; off; off >>= 1) s += __shfl_xor(s, off);
    __shared__ float red[4];
    if ((tid & 63) == 0) red[tid >> 6] = s;
    __syncthreads();
    float tot = red[0] + red[1] + red[2] + red[3];
    float sc = rsqrtf(tot * (1.f / DMODEL) + 1e-5f);
    float4 wv = *(const float4*)(w + tid * 4);
    u16* o = out + (size_t)row * DMODEL + tid * 4;
    u16 ov[4] = { f2bf(v[0] * sc * wv.x), f2bf(v[1] * sc * wv.y),
                  f2bf(v[2] * sc * wv.z), f2bf(v[3] * sc * wv.w) };
    *(uint2*)o = *(const uint2*)ov;
}

// ---------------- NT GEMM: C[M,N] = A[M,K] @ B[N,K]^T, bf16 in, fp32 acc ----------------
// global_load_lds staging (16B/lane); XOR swizzle folded into per-lane global column.
template<int EPI>
__global__ __launch_bounds__(256) void gemm_nt(
    const u16* __restrict__ A, const u16* __restrict__ B,
    int N, int K, int lda, int ntiles,
    u16* __restrict__ Cb, float* __restrict__ Cf)
{
    __shared__ __align__(16) u16 As[128 * 64];
    __shared__ __align__(16) u16 Bs[128 * 64];
    const int GM = 8;
    int gsz = GM * ntiles;
    int bid = blockIdx.x;
    int grp = bid / gsz, rem = bid % gsz;
    int m0 = (grp * GM + (rem % GM)) * 128;
    int n0 = (rem / GM) * 128;

    int tid = threadIdx.x;
    int lane = tid & 63, wv = tid >> 6;
    int wm = wv & 1, wn = wv >> 1;
    int q = lane >> 4, mr = lane & 15;

    f32x4 acc[4][4];
    #pragma unroll
    for (int i = 0; i < 4; i++)
        #pragma unroll
        for (int j = 0; j < 4; j++) acc[i][j] = (f32x4){0.f, 0.f, 0.f, 0.f};

    for (int kt = 0; kt < K; kt += 64) {
        #pragma unroll
        for (int ps = 0; ps < 4; ++ps) {
            int rb = ps * 32 + wv * 8;
            int r = rb + (lane >> 3);
            int scl = (lane & 7) ^ (r & 7);
            async16(&As[rb * 64], A + (size_t)(m0 + r) * lda + kt + scl * 8);
        }
        #pragma unroll
        for (int ps = 0; ps < 4; ++ps) {
            int rb = ps * 32 + wv * 8;
            int r = rb + (lane >> 3);
            int scl = (lane & 7) ^ (r & 7);
            int gn = n0 + r;
            if (gn < N)
                async16(&Bs[rb * 64], B + (size_t)gn * K + kt + scl * 8);
        }
        __syncthreads();
        #pragma unroll
        for (int kk = 0; kk < 2; ++kk) {
            bf16x8 af[4], bfr[4];
            #pragma unroll
            for (int mi = 0; mi < 4; ++mi) {
                int r = wm * 64 + mi * 16 + mr;
                int c = (kk * 4 + q) ^ (r & 7);
                af[mi] = *(const bf16x8*)&As[r * 64 + c * 8];
            }
            #pragma unroll
            for (int ni = 0; ni < 4; ++ni) {
                int r = wn * 64 + ni * 16 + mr;
                int c = (kk * 4 + q) ^ (r & 7);
                bfr[ni] = *(const bf16x8*)&Bs[r * 64 + c * 8];
            }
            #pragma unroll
            for (int mi = 0; mi < 4; ++mi)
                #pragma unroll
                for (int ni = 0; ni < 4; ++ni)
                    acc[mi][ni] = __builtin_amdgcn_mfma_f32_16x16x32_bf16(
                        af[mi], bfr[ni], acc[mi][ni], 0, 0, 0);
        }
        __syncthreads();
    }

    #pragma unroll
    for (int mi = 0; mi < 4; ++mi) {
        #pragma unroll
        for (int ni = 0; ni < 4; ++ni) {
            int gn = n0 + wn * 64 + ni * 16 + mr;
            if (gn < N) {
                #pragma unroll
                for (int r4 = 0; r4 < 4; ++r4) {
                    int gm = m0 + wm * 64 + mi * 16 + q * 4 + r4;
                    float v = acc[mi][ni][r4];
                    size_t idx = (size_t)gm * N + gn;
                    if (EPI == 0)      Cb[idx] = f2bf(v);
                    else if (EPI == 1) Cb[idx] = f2bf(bf2f(Cb[idx]) + v);
                    else               Cf[idx] = v;
                }
            }
        }
    }
}

// ---------------- halo save ----------------
__global__ __launch_bounds__(256) void halo_kernel(
    const u16* __restrict__ zx, u16* __restrict__ halo)
{
    int c = blockIdx.x * 256 + threadIdx.x;
    int idx = blockIdx.y;
    int b = blockIdx.z;
    int bi = idx / 3, r = idx % 3;
    int t = (bi + 1) * TCH - 3 + r;
    halo[(((size_t)b * (NCH - 1) + bi) * 3 + r) * CONVD + c] =
        zx[((size_t)b * SEQ + t) * DPROJ + DINNER + c];
}

// ---------------- depthwise causal conv + silu, in-place ----------------
__global__ __launch_bounds__(256) void convip_kernel(
    u16* __restrict__ zx, const float* __restrict__ cw, const float* __restrict__ cb,
    const u16* __restrict__ halo)
{
    int c = blockIdx.x * 256 + threadIdx.x;
    int ci = blockIdx.y;
    int b = blockIdx.z;
    float w0 = cw[c * 4 + 0], w1 = cw[c * 4 + 1];
    float w2 = cw[c * 4 + 2], w3 = cw[c * 4 + 3];
    float bias = cb[c];
    float h3 = 0.f, h2 = 0.f, h1 = 0.f;
    if (ci > 0) {
        const u16* hb = halo + (((size_t)b * (NCH - 1) + (ci - 1)) * 3) * CONVD + c;
        h3 = bf2f(hb[0 * CONVD]);
        h2 = bf2f(hb[1 * CONVD]);
        h1 = bf2f(hb[2 * CONVD]);
    }
    u16* p = zx + ((size_t)b * SEQ + (size_t)ci * TCH) * DPROJ + DINNER + c;
    #pragma unroll 4
    for (int t = 0; t < TCH; ++t) {
        float xr = bf2f(*p);
        float v = bias + w0 * h3 + w1 * h2 + w2 * h1 + w3 * xr;
        *p = f2bf(v / (1.f + expf(-v)));
        h3 = h2; h2 = h1; h1 = xr;
        p += DPROJ;
    }
}

// ================= SSD pass 1: per-chunk Hinc = Bw^T @ X (MFMA), dt cumsum =================
__global__ __launch_bounds__(256) void ssd_p1(
    const u16* __restrict__ zx,
    const float* __restrict__ dtb, const float* __restrict__ Alog,
    u16* __restrict__ cs, float* __restrict__ scum_g, float* __restrict__ sdt_g,
    float* __restrict__ dAck)
{
    int ck = blockIdx.x, hd = blockIdx.y, b = blockIdx.z;
    int tid = threadIdx.x;
    int wv = tid >> 6, lane = tid & 63, q = lane >> 4, mr = lane & 15;

    __shared__ __align__(16) u16 BwT[128 * 136];
    __shared__ __align__(16) u16 XT1[64 * 136];
    __shared__ float scumL[256], sdtL[256], swL[256];

    float An = -expf(Alog[hd]);
    float dtbF = dtb[hd];

    {
        size_t row = (size_t)b * SEQ + ck * QS + tid;
        float xx = bf2f(zx[row * DPROJ + DTOFF + hd]) + dtbF;
        float dt = (xx > 20.f) ? xx : log1pf(expf(xx));
        sdtL[tid] = dt;
        scumL[tid] = dt;
        __syncthreads();
        for (int ofs = 1; ofs < 256; ofs <<= 1) {
            float v = scumL[tid];
            float u = (tid >= ofs) ? scumL[tid - ofs] : 0.f;
            __syncthreads();
            scumL[tid] = v + u;
            __syncthreads();
        }
        float cumQ = scumL[255];
        swL[tid] = expf(An * (cumQ - scumL[tid])) * dt;
        size_t gbase = (((size_t)b * NH + hd) * NQ + ck) * QS;
        scum_g[gbase + tid] = scumL[tid];
        sdt_g[gbase + tid] = dt;
        if (tid == 0) dAck[((size_t)b * NH + hd) * NQ + ck] = expf(An * cumQ);
    }

    f32x4 hacc[2][4];
    #pragma unroll
    for (int i = 0; i < 2; i++)
        #pragma unroll
        for (int j = 0; j < 4; j++) hacc[i][j] = (f32x4){0.f, 0.f, 0.f, 0.f};

    int n0 = wv * 32;
    int jj = tid & 127, hi = tid >> 7;

    for (int half = 0; half < 2; ++half) {
        __syncthreads();
        size_t rowj = ((size_t)b * SEQ + ck * QS + half * 128 + jj) * DPROJ;
        float wj = swL[half * 128 + jj];
        #pragma unroll
        for (int it = 0; it < 8; ++it) {
            int nc = hi * 8 + it;
            uint4 v = *(const uint4*)(zx + rowj + BOFF + nc * 8);
            float f[8]; unpack8(v, f);
            #pragma unroll
            for (int u = 0; u < 8; ++u)
                BwT[(nc * 8 + u) * 136 + jj] = f2bf(f[u] * wj);
        }
        #pragma unroll
        for (int it = 0; it < 4; ++it) {
            int pc = hi * 4 + it;
            uint4 v = *(const uint4*)(zx + rowj + XOFF + hd * 64 + pc * 8);
            const u16* vp = (const u16*)&v;
            #pragma unroll
            for (int u = 0; u < 8; ++u)
                XT1[(pc * 8 + u) * 136 + jj] = vp[u];
        }
        __syncthreads();
        #pragma unroll
        for (int kk = 0; kk < 4; ++kk) {
            bf16x8 af[2], bx[4];
            #pragma unroll
            for (int it = 0; it < 2; ++it)
                af[it] = *(const bf16x8*)&BwT[(n0 + it * 16 + mr) * 136 + kk * 32 + q * 8];
            #pragma unroll
            for (int pt = 0; pt < 4; ++pt)
                bx[pt] = *(const bf16x8*)&XT1[(pt * 16 + mr) * 136 + kk * 32 + q * 8];
            #pragma unroll
            for (int it = 0; it < 2; ++it)
                #pragma unroll
                for (int pt = 0; pt < 4; ++pt)
                    hacc[it][pt] = __builtin_amdgcn_mfma_f32_16x16x32_bf16(
                        af[it], bx[pt], hacc[it][pt], 0, 0, 0);
        }
    }

    size_t basec = (((size_t)b * NH + hd) * NQ + ck) * 8192;
    #pragma unroll
    for (int it = 0; it < 2; ++it)
        #pragma unroll
        for (int pt = 0; pt < 4; ++pt)
            #pragma unroll
            for (int reg = 0; reg < 4; ++reg) {
                int n = n0 + it * 16 + q * 4 + reg;
                int p = pt * 16 + mr;
                cs[basec + p * 128 + n] = f2bf(hacc[it][pt][reg]);
            }
}

// ================= SSD pass 2: sequential chunk combine, Hinc -> Hstart =================
__global__ __launch_bounds__(256) void ssd_p2(
    u16* __restrict__ cs, const float* __restrict__ dAck)
{
    int hd = blockIdx.y, b = blockIdx.z;
    int off = blockIdx.x * 1024 + threadIdx.x * 4;
    size_t base = (((size_t)b * NH + hd) * NQ) * 8192 + off;
    const float* dA = dAck + ((size_t)b * NH + hd) * NQ;
    float c0 = 0.f, c1 = 0.f, c2 = 0.f, c3 = 0.f;
    for (int ck = 0; ck < NQ; ++ck) {
        u16* p = cs + base + (size_t)ck * 8192;
        uint2 v = *(const uint2*)p;
        float i0 = bf2f((u16)(v.x & 0xFFFF)), i1 = bf2f((u16)(v.x >> 16));
        float i2 = bf2f((u16)(v.y & 0xFFFF)), i3 = bf2f((u16)(v.y >> 16));
        u16 o[4] = { f2bf(c0), f2bf(c1), f2bf(c2), f2bf(c3) };
        *(uint2*)p = *(const uint2*)o;
        float a = dA[ck];
        c0 = fmaf(a, c0, i0); c1 = fmaf(a, c1, i1);
        c2 = fmaf(a, c2, i2); c3 = fmaf(a, c3, i3);
    }
}

// ================= SSD pass 3: R0 loop structure + shuffle-free K=16 Y-MFMA =================
// Flat grid 2048, XCD-colocated. Wave wv owns contiguous i-panel [wv*64, wv*64+64);
// waves skip fully-masked j-tiles (jtmax=2wv+2). LB(256,3): 4 blocks/CU thrashes
// L2 (R6: FETCH 190->566MB, dur +68%) -- keep 3.
// S^T[j][i] = B@C^T via K=32 MFMA; its D-layout (row j = q*4+reg) IS the
// 16x16x16 A-frag layout (k = q*4+u), so decayed/masked S feeds Y += S@X
// directly -- the former ~770 serial ds_bpermute per block are gone.
__global__ __launch_bounds__(256, 3) void ssd_p3(
    u16* __restrict__ zx,
    const float* __restrict__ Alog, const float* __restrict__ Dp,
    const u16* __restrict__ cs,
    const float* __restrict__ scum_g, const float* __restrict__ sdt_g)
{
    int bid = blockIdx.x;
    int xcd = bid & 7;
    int ixd = bid >> 3;              // 0..255
    int hd  = ixd & 31;
    int pr  = (xcd << 3) | (ixd >> 5);   // 0..63, constant per XCD
    int b   = pr >> 4;
    int ck  = pr & 15;

    int tid = threadIdx.x;
    int wv = tid >> 6, lane = tid & 63, q = lane >> 4, mr = lane & 15;
    int i0 = wv * 64;

    __shared__ __align__(16) u16 XT[64 * 264];   // x^T [p][j], pad 8
    __shared__ __align__(16) float scumL[256];
    __shared__ __align__(16) float sdtL[256];

    float An = -expf(Alog[hd]);
    float Dh = Dp[hd];

    {
        size_t gbase = (((size_t)b * NH + hd) * NQ + ck) * QS;
        scumL[tid] = scum_g[gbase + tid];
        sdtL[tid] = sdt_g[gbase + tid];
    }
    // stage X^T (thread = column j)
    {
        size_t rowj = ((size_t)b * SEQ + ck * QS + tid) * DPROJ + XOFF + hd * 64;
        #pragma unroll
        for (int pc = 0; pc < 8; ++pc) {
            uint4 v = *(const uint4*)(zx + rowj + pc * 8);
            const u16* vp = (const u16*)&v;
            #pragma unroll
            for (int u = 0; u < 8; ++u)
                XT[(pc * 8 + u) * 264 + tid] = vp[u];
        }
    }

    f32x4 Y[4][4];
    #pragma unroll
    for (int i = 0; i < 4; i++)
        #pragma unroll
        for (int j = 0; j < 4; j++) Y[i][j] = (f32x4){0.f, 0.f, 0.f, 0.f};

    const size_t rowC = ((size_t)b * SEQ + ck * QS) * DPROJ;
    size_t basec = (((size_t)b * NH + hd) * NQ + ck) * 8192;

    __syncthreads();   // the only barrier

    // Y1 = C @ Hstart (both operands direct from global), then row-decay scale
    #pragma unroll
    for (int kk = 0; kk < 4; ++kk) {
        bf16x8 cf[4], hb[4];
        #pragma unroll
        for (int it = 0; it < 4; ++it)
            cf[it] = *(const bf16x8*)(zx + rowC + (size_t)(i0 + it * 16 + mr) * DPROJ
                                      + COFF + kk * 32 + q * 8);
        #pragma unroll
        for (int pt = 0; pt < 4; ++pt)
            hb[pt] = *(const bf16x8*)(cs + basec + (size_t)(pt * 16 + mr) * 128
                                      + kk * 32 + q * 8);
        #pragma unroll
        for (int it = 0; it < 4; ++it)
            #pragma unroll
            for (int pt = 0; pt < 4; ++pt)
                Y[it][pt] = __builtin_amdgcn_mfma_f32_16x16x32_bf16(
                    cf[it], hb[pt], Y[it][pt], 0, 0, 0);
    }
    #pragma unroll
    for (int it = 0; it < 4; ++it)
        #pragma unroll
        for (int reg = 0; reg < 4; ++reg) {
            float f = expf(An * scumL[i0 + it * 16 + q * 4 + reg]);
            #pragma unroll
            for (int pt = 0; pt < 4; ++pt) Y[it][pt][reg] *= f;
        }

    // per-it row cumsum (for R_i factor), hoisted out of the jt loop
    float sci[4];
    #pragma unroll
    for (int it = 0; it < 4; ++it) sci[it] = scumL[i0 + it * 16 + mr];

    // intra-chunk causal part: wave-local 32-wide j-tiles, no barriers
    int jtmax = 2 * wv + 2;
    for (int jt = 0; jt < jtmax; ++jt) {
        int jt0 = jt * 32;
        float ref = scumL[jt0 + 15];

        // S^T[j][i] = B @ C^T, operands direct from global (L1-hot)
        f32x4 ST[2][4];
        #pragma unroll
        for (int jm = 0; jm < 2; ++jm)
            #pragma unroll
            for (int it = 0; it < 4; ++it) ST[jm][it] = (f32x4){0.f, 0.f, 0.f, 0.f};
        #pragma unroll
        for (int kk = 0; kk < 4; ++kk) {
            bf16x8 ba[2], cf[4];
            #pragma unroll
            for (int jm = 0; jm < 2; ++jm)
                ba[jm] = *(const bf16x8*)(zx + rowC + (size_t)(jt0 + jm * 16 + mr) * DPROJ
                                          + BOFF + kk * 32 + q * 8);
            #pragma unroll
            for (int it = 0; it < 4; ++it)
                cf[it] = *(const bf16x8*)(zx + rowC + (size_t)(i0 + it * 16 + mr) * DPROJ
                                          + COFF + kk * 32 + q * 8);
            #pragma unroll
            for (int jm = 0; jm < 2; ++jm)
                #pragma unroll
                for (int it = 0; it < 4; ++it)
                    ST[jm][it] = __builtin_amdgcn_mfma_f32_16x16x32_bf16(
                        ba[jm], cf[it], ST[jm][it], 0, 0, 0);
        }

        // decay: Q_j from aligned float4 LDS reads (no shuffles), R_i per it
        float Qf[2][4];
        #pragma unroll
        for (int jm = 0; jm < 2; ++jm) {
            float4 scq = *(const float4*)&scumL[jt0 + jm * 16 + q * 4];
            float4 sdq = *(const float4*)&sdtL[jt0 + jm * 16 + q * 4];
            Qf[jm][0] = expf(An * (ref - scq.x)) * sdq.x;
            Qf[jm][1] = expf(An * (ref - scq.y)) * sdq.y;
            Qf[jm][2] = expf(An * (ref - scq.z)) * sdq.z;
            Qf[jm][3] = expf(An * (ref - scq.w)) * sdq.w;
        }

        bf16x4 xf[2][4];
        #pragma unroll
        for (int jm = 0; jm < 2; ++jm)
            #pragma unroll
            for (int pt = 0; pt < 4; ++pt)
                xf[jm][pt] = *(const bf16x4*)&XT[(pt * 16 + mr) * 264 + jt0 + jm * 16 + q * 4];

        // ST[jm][it][u] = S^T[j = jt0+jm*16+q*4+u][i = i0+it*16+mr] -> K=16 A-frag
        #pragma unroll
        for (int it = 0; it < 4; ++it) {
            float Ri = expf(An * (sci[it] - ref));
            int ig = i0 + it * 16 + mr;
            #pragma unroll
            for (int jm = 0; jm < 2; ++jm) {
                u16 marr[4];
                #pragma unroll
                for (int u = 0; u < 4; ++u) {
                    int jg = jt0 + jm * 16 + q * 4 + u;
                    float m = (jg <= ig) ? Ri * Qf[jm][u] * ST[jm][it][u] : 0.f;
                    marr[u] = f2bf(m);
                }
                bf16x4 mf;
                __builtin_memcpy(&mf, marr, 8);
                #pragma unroll
                for (int pt = 0; pt < 4; ++pt)
                    Y[it][pt] = mfma16bf(mf, xf[jm][pt], Y[it][pt]);
            }
        }
    }

    // epilogue: y = Y + D*x, write over x cols
    #pragma unroll
    for (int it = 0; it < 4; ++it)
        #pragma unroll
        for (int pt = 0; pt < 4; ++pt)
            #pragma unroll
            for (int reg = 0; reg < 4; ++reg) {
                int i = i0 + it * 16 + q * 4 + reg;
                int p = pt * 16 + mr;
                float xv = bf2f(XT[p * 264 + i]);
                float val = Y[it][pt][reg] + Dh * xv;
                zx[((size_t)b * SEQ + ck * QS + i) * DPROJ + XOFF + hd * 64 + p] = f2bf(val);
            }
}

// ---------------- y * silu(z) then rmsnorm(gnorm_w f32) ----------------
__global__ __launch_bounds__(256) void gatenorm_kernel(
    u16* __restrict__ zx, const float* __restrict__ gw)
{
    int row = blockIdx.x, tid = threadIdx.x;
    u16* zr = zx + (size_t)row * DPROJ;
    float v[8];
    float s = 0.f;
    #pragma unroll
    for (int i = 0; i < 8; ++i) {
        int idx = i * 256 + tid;
        float zv = bf2f(zr[idx]);
        float gate = zv / (1.f + expf(-zv));
        float val = bf2f(zr[DINNER + idx]) * gate;
        v[i] = val;
        s += val * val;
    }
    #pragma unroll
    for (int off = 32; off; off >>= 1) s += __shfl_xor(s, off);
    __shared__ float red[4];
    if ((tid & 63) == 0) red[tid >> 6] = s;
    __syncthreads();
    float tot = red[0] + red[1] + red[2] + red[3];
    float sc = rsqrtf(tot * (1.f / DINNER) + 1e-5f);
    #pragma unroll
    for (int i = 0; i < 8; ++i) {
        int idx = i * 256 + tid;
        zr[DINNER + idx] = f2bf(v[i] * sc * gw[idx]);
    }
}

extern "C" void kernel_launch(void* const* d_in, const int* in_sizes, int n_in,
                              void* d_out, int out_size, void* d_ws, size_t ws_size,
                              hipStream_t stream) {
    const int*   x          = (const int*)d_in[0];
    const float* emb        = (const float*)d_in[1];
    const float* in_proj_w  = (const float*)d_in[2];
    const float* conv_w     = (const float*)d_in[3];
    const float* conv_b     = (const float*)d_in[4];
    const float* dt_bias    = (const float*)d_in[5];
    const float* A_log      = (const float*)d_in[6];
    const float* Dp         = (const float*)d_in[7];
    const float* gnorm_w    = (const float*)d_in[8];
    const float* out_proj_w = (const float*)d_in[9];
    const float* rms_w      = (const float*)d_in[10];
    const float* norm_f_w   = (const float*)d_in[11];
    const float* lm_head_w  = (const float*)d_in[12];
    float* out = (float*)d_out;

    char* w = (char*)d_ws;
    u16* h       = (u16*)w; w += (size_t)ROWS * DMODEL * 2;
    u16* zx      = (u16*)w; w += (size_t)ROWS * DPROJ * 2;
    char* scratch = w;      w += (size_t)NBATCH * NH * NQ * 8192 * 2;  // 32 MiB
    u16* wA      = (u16*)w; w += (size_t)DPROJ * DMODEL * 2;
    u16* wB      = (u16*)w; w += (size_t)DMODEL * DINNER * 2;
    float* scum_g = (float*)w; w += (size_t)NBATCH * NH * NQ * QS * 4;
    float* sdt_g  = (float*)w; w += (size_t)NBATCH * NH * NQ * QS * 4;
    float* dAck   = (float*)w; w += (size_t)NBATCH * NH * NQ * 4;
    u16* normed  = (u16*)scratch;
    u16* halo    = (u16*)scratch;
    u16* cs      = (u16*)scratch;

    embed_kernel<<<ROWS, 256, 0, stream>>>(x, emb, h);

    const int nInW = DPROJ * DMODEL;
    const int nOutW = DMODEL * DINNER;
    const int nHeadW = 64 * DMODEL;

    for (int l = 0; l < 4; ++l) {
        cvt_kernel<<<nInW / 1024, 256, 0, stream>>>(
            in_proj_w + (size_t)l * nInW, wA, nInW);
        cvt_kernel<<<nOutW / 1024, 256, 0, stream>>>(
            out_proj_w + (size_t)l * nOutW, wB, nOutW);
        rmsnorm_kernel<<<ROWS, 256, 0, stream>>>(h, rms_w + l * DMODEL, normed);
        gemm_nt<0><<<128 * 35, 256, 0, stream>>>(
            normed, wA, DPROJ, DMODEL, DMODEL, 35, zx, nullptr);
        halo_kernel<<<dim3(9, (NCH - 1) * 3, NBATCH), 256, 0, stream>>>(zx, halo);
        convip_kernel<<<dim3(9, NCH, NBATCH), 256, 0, stream>>>(
            zx, conv_w + (size_t)l * CONVD * 4, conv_b + (size_t)l * CONVD, halo);
        ssd_p1<<<dim3(NQ, NH, NBATCH), 256, 0, stream>>>(
            zx, dt_bias + l * NH, A_log + l * NH, cs, scum_g, sdt_g, dAck);
        ssd_p2<<<dim3(8, NH, NBATCH), 256, 0, stream>>>(cs, dAck);
        ssd_p3<<<NQ * NH * NBATCH, 256, 0, stream>>>(
            zx, A_log + l * NH, Dp + l * NH, cs, scum_g, sdt_g);
        gatenorm_kernel<<<ROWS, 256, 0, stream>>>(zx, gnorm_w + (size_t)l * DINNER);
        gemm_nt<1><<<128 * 8, 256, 0, stream>>>(
            zx + DINNER, wB, DMODEL, DINNER, DPROJ, 8, h, nullptr);
    }

    rmsnorm_kernel<<<ROWS, 256, 0, stream>>>(h, norm_f_w, normed);
    cvt_kernel<<<nHeadW / 1024, 256, 0, stream>>>(lm_head_w, wA, nHeadW);
    gemm_nt<2><<<128 * 1, 256, 0, stream>>>(
        normed, wA, 64, DMODEL, DMODEL, 1, nullptr, out);
}

// Round 8
// 2579.628 us; speedup vs baseline: 1.2636x; 1.0052x over previous
//
#include <hip/hip_runtime.h>
#include <hip/hip_bf16.h>

typedef unsigned short u16;
typedef unsigned int u32;
typedef __attribute__((ext_vector_type(8))) __bf16 bf16x8;
typedef __attribute__((ext_vector_type(4))) __bf16 bf16x4;
typedef __attribute__((ext_vector_type(4))) short s16x4;
typedef __attribute__((ext_vector_type(4))) float f32x4;

#define SEQ 4096
#define NBATCH 4
#define DMODEL 1024
#define DINNER 2048
#define DSTATE 128
#define NH 32
#define CONVD 2304
#define DPROJ 4384
#define ROWS (NBATCH*SEQ)   // 16384
#define TCH 256             // conv time-chunk
#define NCH (SEQ/TCH)       // 16 chunks -> 15 halo boundaries per batch
#define QS 256              // SSD chunk length
#define NQ (SEQ/QS)         // 16 SSD chunks
#define XOFF DINNER                   // 2048: conv'd x columns
#define BOFF (2*DINNER)               // 4096: B columns
#define COFF (2*DINNER + DSTATE)      // 4224: C columns
#define DTOFF (2*DINNER + 2*DSTATE)   // 4352: dt columns

__device__ __forceinline__ float bf2f(u16 v) {
    u32 x = ((u32)v) << 16;
    float f;
    __builtin_memcpy(&f, &x, 4);
    return f;
}
__device__ __forceinline__ u16 f2bf(float f) {
    u32 x;
    __builtin_memcpy(&x, &f, 4);
    u32 r = (x + 0x7FFFu + ((x >> 16) & 1u)) >> 16;
    return (u16)r;
}
__device__ __forceinline__ void unpack8(uint4 v, float* f) {
    u32 w0 = v.x, w1 = v.y, w2 = v.z, w3 = v.w;
    f[0] = bf2f((u16)(w0 & 0xFFFF)); f[1] = bf2f((u16)(w0 >> 16));
    f[2] = bf2f((u16)(w1 & 0xFFFF)); f[3] = bf2f((u16)(w1 >> 16));
    f[4] = bf2f((u16)(w2 & 0xFFFF)); f[5] = bf2f((u16)(w2 >> 16));
    f[6] = bf2f((u16)(w3 & 0xFFFF)); f[7] = bf2f((u16)(w3 >> 16));
}

// 16x16x16 bf16 MFMA: A-frag k = q*4+u matches the 16x16 D-layout row = q*4+reg,
// so the S^T MFMA output feeds this A-operand with ZERO cross-lane shuffles.
__device__ __forceinline__ f32x4 mfma16bf(bf16x4 a, bf16x4 b, f32x4 c) {
#if __has_builtin(__builtin_amdgcn_mfma_f32_16x16x16bf16_1k)
    s16x4 as, bs;
    __builtin_memcpy(&as, &a, 8);
    __builtin_memcpy(&bs, &b, 8);
    return __builtin_amdgcn_mfma_f32_16x16x16bf16_1k(as, bs, c, 0, 0, 0);
#else
    f32x4 d = c;
    asm volatile("v_mfma_f32_16x16x16_bf16 %0, %1, %2, %0"
                 : "+v"(d) : "v"(a), "v"(b));
    return d;
#endif
}

// async global->LDS, 16B/lane: LDS dest = wave-uniform base + lane*16
__device__ __forceinline__ void async16(u16* lds_base, const u16* g) {
    __builtin_amdgcn_global_load_lds(
        (const __attribute__((address_space(1))) u32*)g,
        (__attribute__((address_space(3))) u32*)(u32)(size_t)lds_base,
        16, 0, 0);
}

// ---------------- f32 -> bf16 weight panel conversion ----------------
__global__ __launch_bounds__(256) void cvt_kernel(
    const float* __restrict__ in, u16* __restrict__ out, int n)
{
    int i = (blockIdx.x * 256 + threadIdx.x) * 4;
    if (i < n) {
        float4 v = *(const float4*)(in + i);
        u16 o[4] = { f2bf(v.x), f2bf(v.y), f2bf(v.z), f2bf(v.w) };
        *(uint2*)(out + i) = *(const uint2*)o;
    }
}

// ---------------- embedding: f32 table -> bf16 rows ----------------
__global__ __launch_bounds__(256) void embed_kernel(
    const int* __restrict__ x, const float* __restrict__ emb, u16* __restrict__ h)
{
    int row = blockIdx.x, tid = threadIdx.x;
    int id = x[row];
    float4 v = *(const float4*)(emb + (size_t)id * DMODEL + tid * 4);
    u16 o[4] = { f2bf(v.x), f2bf(v.y), f2bf(v.z), f2bf(v.w) };
    *(uint2*)(h + (size_t)row * DMODEL + tid * 4) = *(const uint2*)o;
}

// ---------------- rmsnorm (bf16 in, f32 weight -> bf16 out) ----------------
__global__ __launch_bounds__(256) void rmsnorm_kernel(
    const u16* __restrict__ in, const float* __restrict__ w, u16* __restrict__ out)
{
    int row = blockIdx.x, tid = threadIdx.x;
    const u16* r = in + (size_t)row * DMODEL + tid * 4;
    float v[4];
    v[0] = bf2f(r[0]); v[1] = bf2f(r[1]); v[2] = bf2f(r[2]); v[3] = bf2f(r[3]);
    float s = v[0]*v[0] + v[1]*v[1] + v[2]*v[2] + v[3]*v[3];
    #pragma unroll
    for (int off = 32; off; off >>= 1) s += __shfl_xor(s, off);
    __shared__ float red[4];
    if ((tid & 63) == 0) red[tid >> 6] = s;
    __syncthreads();
    float tot = red[0] + red[1] + red[2] + red[3];
    float sc = rsqrtf(tot * (1.f / DMODEL) + 1e-5f);
    float4 wv = *(const float4*)(w + tid * 4);
    u16* o = out + (size_t)row * DMODEL + tid * 4;
    u16 ov[4] = { f2bf(v[0] * sc * wv.x), f2bf(v[1] * sc * wv.y),
                  f2bf(v[2] * sc * wv.z), f2bf(v[3] * sc * wv.w) };
    *(uint2*)o = *(const uint2*)ov;
}

// ---------------- NT GEMM: C[M,N] = A[M,K] @ B[N,K]^T, bf16 in, fp32 acc ----------------
// global_load_lds staging (16B/lane); XOR swizzle folded into per-lane global column.
// XCD-chunked bijective swizzle (T1): each XCD gets a contiguous chunk of the
// M-first ordering, so the group's 2MB A-slab persists in its 4MB L2 and the
// 8 blocks sharing a B tile co-locate. All grids are %8==0.
template<int EPI>
__global__ __launch_bounds__(256) void gemm_nt(
    const u16* __restrict__ A, const u16* __restrict__ B,
    int N, int K, int lda, int ntiles,
    u16* __restrict__ Cb, float* __restrict__ Cf)
{
    __shared__ __align__(16) u16 As[128 * 64];
    __shared__ __align__(16) u16 Bs[128 * 64];
    const int GM = 8;
    int gsz = GM * ntiles;
    int nwg = gridDim.x;
    int bid = (blockIdx.x & 7) * (nwg >> 3) + (blockIdx.x >> 3);
    int grp = bid / gsz, rem = bid % gsz;
    int m0 = (grp * GM + (rem % GM)) * 128;
    int n0 = (rem / GM) * 128;

    int tid = threadIdx.x;
    int lane = tid & 63, wv = tid >> 6;
    int wm = wv & 1, wn = wv >> 1;
    int q = lane >> 4, mr = lane & 15;

    f32x4 acc[4][4];
    #pragma unroll
    for (int i = 0; i < 4; i++)
        #pragma unroll
        for (int j = 0; j < 4; j++) acc[i][j] = (f32x4){0.f, 0.f, 0.f, 0.f};

    for (int kt = 0; kt < K; kt += 64) {
        #pragma unroll
        for (int ps = 0; ps < 4; ++ps) {
            int rb = ps * 32 + wv * 8;
            int r = rb + (lane >> 3);
            int scl = (lane & 7) ^ (r & 7);
            async16(&As[rb * 64], A + (size_t)(m0 + r) * lda + kt + scl * 8);
        }
        #pragma unroll
        for (int ps = 0; ps < 4; ++ps) {
            int rb = ps * 32 + wv * 8;
            int r = rb + (lane >> 3);
            int scl = (lane & 7) ^ (r & 7);
            int gn = n0 + r;
            if (gn < N)
                async16(&Bs[rb * 64], B + (size_t)gn * K + kt + scl * 8);
        }
        __syncthreads();
        #pragma unroll
        for (int kk = 0; kk < 2; ++kk) {
            bf16x8 af[4], bfr[4];
            #pragma unroll
            for (int mi = 0; mi < 4; ++mi) {
                int r = wm * 64 + mi * 16 + mr;
                int c = (kk * 4 + q) ^ (r & 7);
                af[mi] = *(const bf16x8*)&As[r * 64 + c * 8];
            }
            #pragma unroll
            for (int ni = 0; ni < 4; ++ni) {
                int r = wn * 64 + ni * 16 + mr;
                int c = (kk * 4 + q) ^ (r & 7);
                bfr[ni] = *(const bf16x8*)&Bs[r * 64 + c * 8];
            }
            #pragma unroll
            for (int mi = 0; mi < 4; ++mi)
                #pragma unroll
                for (int ni = 0; ni < 4; ++ni)
                    acc[mi][ni] = __builtin_amdgcn_mfma_f32_16x16x32_bf16(
                        af[mi], bfr[ni], acc[mi][ni], 0, 0, 0);
        }
        __syncthreads();
    }

    #pragma unroll
    for (int mi = 0; mi < 4; ++mi) {
        #pragma unroll
        for (int ni = 0; ni < 4; ++ni) {
            int gn = n0 + wn * 64 + ni * 16 + mr;
            if (gn < N) {
                #pragma unroll
                for (int r4 = 0; r4 < 4; ++r4) {
                    int gm = m0 + wm * 64 + mi * 16 + q * 4 + r4;
                    float v = acc[mi][ni][r4];
                    size_t idx = (size_t)gm * N + gn;
                    if (EPI == 0)      Cb[idx] = f2bf(v);
                    else if (EPI == 1) Cb[idx] = f2bf(bf2f(Cb[idx]) + v);
                    else               Cf[idx] = v;
                }
            }
        }
    }
}

// ---------------- halo save ----------------
__global__ __launch_bounds__(256) void halo_kernel(
    const u16* __restrict__ zx, u16* __restrict__ halo)
{
    int c = blockIdx.x * 256 + threadIdx.x;
    int idx = blockIdx.y;
    int b = blockIdx.z;
    int bi = idx / 3, r = idx % 3;
    int t = (bi + 1) * TCH - 3 + r;
    halo[(((size_t)b * (NCH - 1) + bi) * 3 + r) * CONVD + c] =
        zx[((size_t)b * SEQ + t) * DPROJ + DINNER + c];
}

// ---------------- depthwise causal conv + silu, in-place ----------------
__global__ __launch_bounds__(256) void convip_kernel(
    u16* __restrict__ zx, const float* __restrict__ cw, const float* __restrict__ cb,
    const u16* __restrict__ halo)
{
    int c = blockIdx.x * 256 + threadIdx.x;
    int ci = blockIdx.y;
    int b = blockIdx.z;
    float w0 = cw[c * 4 + 0], w1 = cw[c * 4 + 1];
    float w2 = cw[c * 4 + 2], w3 = cw[c * 4 + 3];
    float bias = cb[c];
    float h3 = 0.f, h2 = 0.f, h1 = 0.f;
    if (ci > 0) {
        const u16* hb = halo + (((size_t)b * (NCH - 1) + (ci - 1)) * 3) * CONVD + c;
        h3 = bf2f(hb[0 * CONVD]);
        h2 = bf2f(hb[1 * CONVD]);
        h1 = bf2f(hb[2 * CONVD]);
    }
    u16* p = zx + ((size_t)b * SEQ + (size_t)ci * TCH) * DPROJ + DINNER + c;
    #pragma unroll 4
    for (int t = 0; t < TCH; ++t) {
        float xr = bf2f(*p);
        float v = bias + w0 * h3 + w1 * h2 + w2 * h1 + w3 * xr;
        *p = f2bf(v / (1.f + expf(-v)));
        h3 = h2; h2 = h1; h1 = xr;
        p += DPROJ;
    }
}

// ================= SSD pass 1: per-chunk Hinc = Bw^T @ X (MFMA), dt cumsum =================
__global__ __launch_bounds__(256) void ssd_p1(
    const u16* __restrict__ zx,
    const float* __restrict__ dtb, const float* __restrict__ Alog,
    u16* __restrict__ cs, float* __restrict__ scum_g, float* __restrict__ sdt_g,
    float* __restrict__ dAck)
{
    int ck = blockIdx.x, hd = blockIdx.y, b = blockIdx.z;
    int tid = threadIdx.x;
    int wv = tid >> 6, lane = tid & 63, q = lane >> 4, mr = lane & 15;

    __shared__ __align__(16) u16 BwT[128 * 136];
    __shared__ __align__(16) u16 XT1[64 * 136];
    __shared__ float scumL[256], sdtL[256], swL[256];

    float An = -expf(Alog[hd]);
    float dtbF = dtb[hd];

    {
        size_t row = (size_t)b * SEQ + ck * QS + tid;
        float xx = bf2f(zx[row * DPROJ + DTOFF + hd]) + dtbF;
        float dt = (xx > 20.f) ? xx : log1pf(expf(xx));
        sdtL[tid] = dt;
        scumL[tid] = dt;
        __syncthreads();
        for (int ofs = 1; ofs < 256; ofs <<= 1) {
            float v = scumL[tid];
            float u = (tid >= ofs) ? scumL[tid - ofs] : 0.f;
            __syncthreads();
            scumL[tid] = v + u;
            __syncthreads();
        }
        float cumQ = scumL[255];
        swL[tid] = expf(An * (cumQ - scumL[tid])) * dt;
        size_t gbase = (((size_t)b * NH + hd) * NQ + ck) * QS;
        scum_g[gbase + tid] = scumL[tid];
        sdt_g[gbase + tid] = dt;
        if (tid == 0) dAck[((size_t)b * NH + hd) * NQ + ck] = expf(An * cumQ);
    }

    f32x4 hacc[2][4];
    #pragma unroll
    for (int i = 0; i < 2; i++)
        #pragma unroll
        for (int j = 0; j < 4; j++) hacc[i][j] = (f32x4){0.f, 0.f, 0.f, 0.f};

    int n0 = wv * 32;
    int jj = tid & 127, hi = tid >> 7;

    for (int half = 0; half < 2; ++half) {
        __syncthreads();
        size_t rowj = ((size_t)b * SEQ + ck * QS + half * 128 + jj) * DPROJ;
        float wj = swL[half * 128 + jj];
        #pragma unroll
        for (int it = 0; it < 8; ++it) {
            int nc = hi * 8 + it;
            uint4 v = *(const uint4*)(zx + rowj + BOFF + nc * 8);
            float f[8]; unpack8(v, f);
            #pragma unroll
            for (int u = 0; u < 8; ++u)
                BwT[(nc * 8 + u) * 136 + jj] = f2bf(f[u] * wj);
        }
        #pragma unroll
        for (int it = 0; it < 4; ++it) {
            int pc = hi * 4 + it;
            uint4 v = *(const uint4*)(zx + rowj + XOFF + hd * 64 + pc * 8);
            const u16* vp = (const u16*)&v;
            #pragma unroll
            for (int u = 0; u < 8; ++u)
                XT1[(pc * 8 + u) * 136 + jj] = vp[u];
        }
        __syncthreads();
        #pragma unroll
        for (int kk = 0; kk < 4; ++kk) {
            bf16x8 af[2], bx[4];
            #pragma unroll
            for (int it = 0; it < 2; ++it)
                af[it] = *(const bf16x8*)&BwT[(n0 + it * 16 + mr) * 136 + kk * 32 + q * 8];
            #pragma unroll
            for (int pt = 0; pt < 4; ++pt)
                bx[pt] = *(const bf16x8*)&XT1[(pt * 16 + mr) * 136 + kk * 32 + q * 8];
            #pragma unroll
            for (int it = 0; it < 2; ++it)
                #pragma unroll
                for (int pt = 0; pt < 4; ++pt)
                    hacc[it][pt] = __builtin_amdgcn_mfma_f32_16x16x32_bf16(
                        af[it], bx[pt], hacc[it][pt], 0, 0, 0);
        }
    }

    size_t basec = (((size_t)b * NH + hd) * NQ + ck) * 8192;
    #pragma unroll
    for (int it = 0; it < 2; ++it)
        #pragma unroll
        for (int pt = 0; pt < 4; ++pt)
            #pragma unroll
            for (int reg = 0; reg < 4; ++reg) {
                int n = n0 + it * 16 + q * 4 + reg;
                int p = pt * 16 + mr;
                cs[basec + p * 128 + n] = f2bf(hacc[it][pt][reg]);
            }
}

// ================= SSD pass 2: sequential chunk combine, Hinc -> Hstart =================
__global__ __launch_bounds__(256) void ssd_p2(
    u16* __restrict__ cs, const float* __restrict__ dAck)
{
    int hd = blockIdx.y, b = blockIdx.z;
    int off = blockIdx.x * 1024 + threadIdx.x * 4;
    size_t base = (((size_t)b * NH + hd) * NQ) * 8192 + off;
    const float* dA = dAck + ((size_t)b * NH + hd) * NQ;
    float c0 = 0.f, c1 = 0.f, c2 = 0.f, c3 = 0.f;
    for (int ck = 0; ck < NQ; ++ck) {
        u16* p = cs + base + (size_t)ck * 8192;
        uint2 v = *(const uint2*)p;
        float i0 = bf2f((u16)(v.x & 0xFFFF)), i1 = bf2f((u16)(v.x >> 16));
        float i2 = bf2f((u16)(v.y & 0xFFFF)), i3 = bf2f((u16)(v.y >> 16));
        u16 o[4] = { f2bf(c0), f2bf(c1), f2bf(c2), f2bf(c3) };
        *(uint2*)p = *(const uint2*)o;
        float a = dA[ck];
        c0 = fmaf(a, c0, i0); c1 = fmaf(a, c1, i1);
        c2 = fmaf(a, c2, i2); c3 = fmaf(a, c3, i3);
    }
}

// ================= SSD pass 3: R0 loop structure + shuffle-free K=16 Y-MFMA =================
// Flat grid 2048, XCD-colocated. Wave wv owns contiguous i-panel [wv*64, wv*64+64);
// waves skip fully-masked j-tiles (jtmax=2wv+2). LB(256,3): 4 blocks/CU thrashes
// L2 (R6: FETCH 190->566MB, dur +68%) -- keep 3.
// S^T[j][i] = B@C^T via K=32 MFMA; its D-layout (row j = q*4+reg) IS the
// 16x16x16 A-frag layout (k = q*4+u), so decayed/masked S feeds Y += S@X
// directly -- no cross-lane shuffles (R7: 183->172us, conflicts 6.4M->1.8M).
__global__ __launch_bounds__(256, 3) void ssd_p3(
    u16* __restrict__ zx,
    const float* __restrict__ Alog, const float* __restrict__ Dp,
    const u16* __restrict__ cs,
    const float* __restrict__ scum_g, const float* __restrict__ sdt_g)
{
    int bid = blockIdx.x;
    int xcd = bid & 7;
    int ixd = bid >> 3;              // 0..255
    int hd  = ixd & 31;
    int pr  = (xcd << 3) | (ixd >> 5);   // 0..63, constant per XCD
    int b   = pr >> 4;
    int ck  = pr & 15;

    int tid = threadIdx.x;
    int wv = tid >> 6, lane = tid & 63, q = lane >> 4, mr = lane & 15;
    int i0 = wv * 64;

    __shared__ __align__(16) u16 XT[64 * 264];   // x^T [p][j], pad 8
    __shared__ __align__(16) float scumL[256];
    __shared__ __align__(16) float sdtL[256];

    float An = -expf(Alog[hd]);
    float Dh = Dp[hd];

    {
        size_t gbase = (((size_t)b * NH + hd) * NQ + ck) * QS;
        scumL[tid] = scum_g[gbase + tid];
        sdtL[tid] = sdt_g[gbase + tid];
    }
    // stage X^T (thread = column j)
    {
        size_t rowj = ((size_t)b * SEQ + ck * QS + tid) * DPROJ + XOFF + hd * 64;
        #pragma unroll
        for (int pc = 0; pc < 8; ++pc) {
            uint4 v = *(const uint4*)(zx + rowj + pc * 8);
            const u16* vp = (const u16*)&v;
            #pragma unroll
            for (int u = 0; u < 8; ++u)
                XT[(pc * 8 + u) * 264 + tid] = vp[u];
        }
    }

    f32x4 Y[4][4];
    #pragma unroll
    for (int i = 0; i < 4; i++)
        #pragma unroll
        for (int j = 0; j < 4; j++) Y[i][j] = (f32x4){0.f, 0.f, 0.f, 0.f};

    const size_t rowC = ((size_t)b * SEQ + ck * QS) * DPROJ;
    size_t basec = (((size_t)b * NH + hd) * NQ + ck) * 8192;

    __syncthreads();   // the only barrier

    // Y1 = C @ Hstart (both operands direct from global), then row-decay scale
    #pragma unroll
    for (int kk = 0; kk < 4; ++kk) {
        bf16x8 cf[4], hb[4];
        #pragma unroll
        for (int it = 0; it < 4; ++it)
            cf[it] = *(const bf16x8*)(zx + rowC + (size_t)(i0 + it * 16 + mr) * DPROJ
                                      + COFF + kk * 32 + q * 8);
        #pragma unroll
        for (int pt = 0; pt < 4; ++pt)
            hb[pt] = *(const bf16x8*)(cs + basec + (size_t)(pt * 16 + mr) * 128
                                      + kk * 32 + q * 8);
        #pragma unroll
        for (int it = 0; it < 4; ++it)
            #pragma unroll
            for (int pt = 0; pt < 4; ++pt)
                Y[it][pt] = __builtin_amdgcn_mfma_f32_16x16x32_bf16(
                    cf[it], hb[pt], Y[it][pt], 0, 0, 0);
    }
    #pragma unroll
    for (int it = 0; it < 4; ++it)
        #pragma unroll
        for (int reg = 0; reg < 4; ++reg) {
            float f = expf(An * scumL[i0 + it * 16 + q * 4 + reg]);
            #pragma unroll
            for (int pt = 0; pt < 4; ++pt) Y[it][pt][reg] *= f;
        }

    // per-it row cumsum (for R_i factor), hoisted out of the jt loop
    float sci[4];
    #pragma unroll
    for (int it = 0; it < 4; ++it) sci[it] = scumL[i0 + it * 16 + mr];

    // intra-chunk causal part: wave-local 32-wide j-tiles, no barriers
    int jtmax = 2 * wv + 2;
    for (int jt = 0; jt < jtmax; ++jt) {
        int jt0 = jt * 32;
        float ref = scumL[jt0 + 15];

        // S^T[j][i] = B @ C^T, operands direct from global (L1-hot)
        f32x4 ST[2][4];
        #pragma unroll
        for (int jm = 0; jm < 2; ++jm)
            #pragma unroll
            for (int it = 0; it < 4; ++it) ST[jm][it] = (f32x4){0.f, 0.f, 0.f, 0.f};
        #pragma unroll
        for (int kk = 0; kk < 4; ++kk) {
            bf16x8 ba[2], cf[4];
            #pragma unroll
            for (int jm = 0; jm < 2; ++jm)
                ba[jm] = *(const bf16x8*)(zx + rowC + (size_t)(jt0 + jm * 16 + mr) * DPROJ
                                          + BOFF + kk * 32 + q * 8);
            #pragma unroll
            for (int it = 0; it < 4; ++it)
                cf[it] = *(const bf16x8*)(zx + rowC + (size_t)(i0 + it * 16 + mr) * DPROJ
                                          + COFF + kk * 32 + q * 8);
            #pragma unroll
            for (int jm = 0; jm < 2; ++jm)
                #pragma unroll
                for (int it = 0; it < 4; ++it)
                    ST[jm][it] = __builtin_amdgcn_mfma_f32_16x16x32_bf16(
                        ba[jm], cf[it], ST[jm][it], 0, 0, 0);
        }

        // decay: Q_j from aligned float4 LDS reads (no shuffles), R_i per it
        float Qf[2][4];
        #pragma unroll
        for (int jm = 0; jm < 2; ++jm) {
            float4 scq = *(const float4*)&scumL[jt0 + jm * 16 + q * 4];
            float4 sdq = *(const float4*)&sdtL[jt0 + jm * 16 + q * 4];
            Qf[jm][0] = expf(An * (ref - scq.x)) * sdq.x;
            Qf[jm][1] = expf(An * (ref - scq.y)) * sdq.y;
            Qf[jm][2] = expf(An * (ref - scq.z)) * sdq.z;
            Qf[jm][3] = expf(An * (ref - scq.w)) * sdq.w;
        }

        bf16x4 xf[2][4];
        #pragma unroll
        for (int jm = 0; jm < 2; ++jm)
            #pragma unroll
            for (int pt = 0; pt < 4; ++pt)
                xf[jm][pt] = *(const bf16x4*)&XT[(pt * 16 + mr) * 264 + jt0 + jm * 16 + q * 4];

        // ST[jm][it][u] = S^T[j = jt0+jm*16+q*4+u][i = i0+it*16+mr] -> K=16 A-frag
        #pragma unroll
        for (int it = 0; it < 4; ++it) {
            float Ri = expf(An * (sci[it] - ref));
            int ig = i0 + it * 16 + mr;
            #pragma unroll
            for (int jm = 0; jm < 2; ++jm) {
                u16 marr[4];
                #pragma unroll
                for (int u = 0; u < 4; ++u) {
                    int jg = jt0 + jm * 16 + q * 4 + u;
                    float m = (jg <= ig) ? Ri * Qf[jm][u] * ST[jm][it][u] : 0.f;
                    marr[u] = f2bf(m);
                }
                bf16x4 mf;
                __builtin_memcpy(&mf, marr, 8);
                #pragma unroll
                for (int pt = 0; pt < 4; ++pt)
                    Y[it][pt] = mfma16bf(mf, xf[jm][pt], Y[it][pt]);
            }
        }
    }

    // epilogue: y = Y + D*x, write over x cols
    #pragma unroll
    for (int it = 0; it < 4; ++it)
        #pragma unroll
        for (int pt = 0; pt < 4; ++pt)
            #pragma unroll
            for (int reg = 0; reg < 4; ++reg) {
                int i = i0 + it * 16 + q * 4 + reg;
                int p = pt * 16 + mr;
                float xv = bf2f(XT[p * 264 + i]);
                float val = Y[it][pt][reg] + Dh * xv;
                zx[((size_t)b * SEQ + ck * QS + i) * DPROJ + XOFF + hd * 64 + p] = f2bf(val);
            }
}

// ---------------- y * silu(z) then rmsnorm(gnorm_w f32) ----------------
__global__ __launch_bounds__(256) void gatenorm_kernel(
    u16* __restrict__ zx, const float* __restrict__ gw)
{
    int row = blockIdx.x, tid = threadIdx.x;
    u16* zr = zx + (size_t)row * DPROJ;
    float v[8];
    float s = 0.f;
    #pragma unroll
    for (int i = 0; i < 8; ++i) {
        int idx = i * 256 + tid;
        float zv = bf2f(zr[idx]);
        float gate = zv / (1.f + expf(-zv));
        float val = bf2f(zr[DINNER + idx]) * gate;
        v[i] = val;
        s += val * val;
    }
    #pragma unroll
    for (int off = 32; off; off >>= 1) s += __shfl_xor(s, off);
    __shared__ float red[4];
    if ((tid & 63) == 0) red[tid >> 6] = s;
    __syncthreads();
    float tot = red[0] + red[1] + red[2] + red[3];
    float sc = rsqrtf(tot * (1.f / DINNER) + 1e-5f);
    #pragma unroll
    for (int i = 0; i < 8; ++i) {
        int idx = i * 256 + tid;
        zr[DINNER + idx] = f2bf(v[i] * sc * gw[idx]);
    }
}

extern "C" void kernel_launch(void* const* d_in, const int* in_sizes, int n_in,
                              void* d_out, int out_size, void* d_ws, size_t ws_size,
                              hipStream_t stream) {
    const int*   x          = (const int*)d_in[0];
    const float* emb        = (const float*)d_in[1];
    const float* in_proj_w  = (const float*)d_in[2];
    const float* conv_w     = (const float*)d_in[3];
    const float* conv_b     = (const float*)d_in[4];
    const float* dt_bias    = (const float*)d_in[5];
    const float* A_log      = (const float*)d_in[6];
    const float* Dp         = (const float*)d_in[7];
    const float* gnorm_w    = (const float*)d_in[8];
    const float* out_proj_w = (const float*)d_in[9];
    const float* rms_w      = (const float*)d_in[10];
    const float* norm_f_w   = (const float*)d_in[11];
    const float* lm_head_w  = (const float*)d_in[12];
    float* out = (float*)d_out;

    char* w = (char*)d_ws;
    u16* h       = (u16*)w; w += (size_t)ROWS * DMODEL * 2;
    u16* zx      = (u16*)w; w += (size_t)ROWS * DPROJ * 2;
    char* scratch = w;      w += (size_t)NBATCH * NH * NQ * 8192 * 2;  // 32 MiB
    u16* wA      = (u16*)w; w += (size_t)DPROJ * DMODEL * 2;
    u16* wB      = (u16*)w; w += (size_t)DMODEL * DINNER * 2;
    float* scum_g = (float*)w; w += (size_t)NBATCH * NH * NQ * QS * 4;
    float* sdt_g  = (float*)w; w += (size_t)NBATCH * NH * NQ * QS * 4;
    float* dAck   = (float*)w; w += (size_t)NBATCH * NH * NQ * 4;
    u16* normed  = (u16*)scratch;
    u16* halo    = (u16*)scratch;
    u16* cs      = (u16*)scratch;

    embed_kernel<<<ROWS, 256, 0, stream>>>(x, emb, h);

    const int nInW = DPROJ * DMODEL;
    const int nOutW = DMODEL * DINNER;
    const int nHeadW = 64 * DMODEL;

    for (int l = 0; l < 4; ++l) {
        cvt_kernel<<<nInW / 1024, 256, 0, stream>>>(
            in_proj_w + (size_t)l * nInW, wA, nInW);
        cvt_kernel<<<nOutW / 1024, 256, 0, stream>>>(
            out_proj_w + (size_t)l * nOutW, wB, nOutW);
        rmsnorm_kernel<<<ROWS, 256, 0, stream>>>(h, rms_w + l * DMODEL, normed);
        gemm_nt<0><<<128 * 35, 256, 0, stream>>>(
            normed, wA, DPROJ, DMODEL, DMODEL, 35, zx, nullptr);
        halo_kernel<<<dim3(9, (NCH - 1) * 3, NBATCH), 256, 0, stream>>>(zx, halo);
        convip_kernel<<<dim3(9, NCH, NBATCH), 256, 0, stream>>>(
            zx, conv_w + (size_t)l * CONVD * 4, conv_b + (size_t)l * CONVD, halo);
        ssd_p1<<<dim3(NQ, NH, NBATCH), 256, 0, stream>>>(
            zx, dt_bias + l * NH, A_log + l * NH, cs, scum_g, sdt_g, dAck);
        ssd_p2<<<dim3(8, NH, NBATCH), 256, 0, stream>>>(cs, dAck);
        ssd_p3<<<NQ * NH * NBATCH, 256, 0, stream>>>(
            zx, A_log + l * NH, Dp + l * NH, cs, scum_g, sdt_g);
        gatenorm_kernel<<<ROWS, 256, 0, stream>>>(zx, gnorm_w + (size_t)l * DINNER);
        gemm_nt<1><<<128 * 8, 256, 0, stream>>>(
            zx + DINNER, wB, DMODEL, DINNER, DPROJ, 8, h, nullptr);
    }

    rmsnorm_kernel<<<ROWS, 256, 0, stream>>>(h, norm_f_w, normed);
    cvt_kernel<<<nHeadW / 1024, 256, 0, stream>>>(lm_head_w, wA, nHeadW);
    gemm_nt<2><<<128 * 1, 256, 0, stream>>>(
        normed, wA, 64, DMODEL, DMODEL, 1, nullptr, out);
}